// Round 4
// baseline (754.945 us; speedup 1.0000x reference)
//
#include <hip/hip_runtime.h>
#include <cstdint>
#include <cstddef>

typedef _Float16 f16;
typedef __attribute__((ext_vector_type(8))) f16 f16x8;
typedef __attribute__((ext_vector_type(4))) f16 f16x4;
typedef __attribute__((ext_vector_type(4))) float f32x4;
typedef __attribute__((ext_vector_type(4))) unsigned int u32x4;

#define M_TOK 8192
#define DDIM 1024
#define HDIM 4096
#define NEXP 4
#define TOTPAD 16896  // >= 16384 + 4*127, rounded to 128

// ---------------- Router: logits -> top2 softmax weights ------------------
// one wave per token; top2-of-softmax + renorm == softmax over top-2 logits.
__global__ __launch_bounds__(256) void router_kernel(
    const float* __restrict__ x, const float* __restrict__ Wr,
    float* __restrict__ wts, int* __restrict__ top2, float2* __restrict__ wpair) {
    __shared__ float wr_s[DDIM * NEXP];
    for (int i = threadIdx.x; i < DDIM * NEXP; i += 256) wr_s[i] = Wr[i];
    __syncthreads();
    const int wave = threadIdx.x >> 6, lane = threadIdx.x & 63;
    const int t = blockIdx.x * 4 + wave;
    float a0 = 0.f, a1 = 0.f, a2 = 0.f, a3 = 0.f;
    const float* xr = x + (size_t)t * DDIM;
    for (int i = 0; i < DDIM; i += 256) {
        const int d = i + lane * 4;
        const float4 v = *(const float4*)(xr + d);
        const float* w0 = &wr_s[d * 4];
        a0 += v.x * w0[0] + v.y * w0[4] + v.z * w0[8]  + v.w * w0[12];
        a1 += v.x * w0[1] + v.y * w0[5] + v.z * w0[9]  + v.w * w0[13];
        a2 += v.x * w0[2] + v.y * w0[6] + v.z * w0[10] + v.w * w0[14];
        a3 += v.x * w0[3] + v.y * w0[7] + v.z * w0[11] + v.w * w0[15];
    }
    for (int off = 32; off > 0; off >>= 1) {
        a0 += __shfl_xor(a0, off, 64);
        a1 += __shfl_xor(a1, off, 64);
        a2 += __shfl_xor(a2, off, 64);
        a3 += __shfl_xor(a3, off, 64);
    }
    if (lane == 0) {
        float lg[4] = {a0, a1, a2, a3};
        int i1 = 0;
        for (int e = 1; e < 4; ++e) if (lg[e] > lg[i1]) i1 = e;
        int i2 = -1;
        for (int e = 0; e < 4; ++e) {
            if (e == i1) continue;
            if (i2 < 0 || lg[e] > lg[i2]) i2 = e;
        }
        const float w1 = 1.0f / (1.0f + expf(lg[i2] - lg[i1]));
        float w[4] = {0.f, 0.f, 0.f, 0.f};
        w[i1] = w1; w[i2] = 1.0f - w1;
        float* o = wts + (size_t)t * 4;
        o[0] = w[0]; o[1] = w[1]; o[2] = w[2]; o[3] = w[3];
        top2[t] = i1 | (i2 << 8);
        wpair[t] = make_float2(w1, 1.0f - w1);
    }
}

// ---------------- count / offsets / fill (sparse routing lists) -----------
__global__ __launch_bounds__(256) void count_kernel(
    const int* __restrict__ top2, int* __restrict__ meta) {
    __shared__ int lc[4];
    if (threadIdx.x < 4) lc[threadIdx.x] = 0;
    __syncthreads();
    const int t = blockIdx.x * 256 + threadIdx.x;
    const int p = top2[t];
    atomicAdd(&lc[p & 0xff], 1);
    atomicAdd(&lc[(p >> 8) & 0xff], 1);
    __syncthreads();
    if (threadIdx.x < 4) atomicAdd(&meta[threadIdx.x], lc[threadIdx.x]);
}

__global__ void offsets_kernel(int* __restrict__ meta) {
    if (threadIdx.x == 0) {
        int off = 0;
        for (int e = 0; e < 4; ++e) {
            const int c = meta[e];
            const int cp = (c + 127) & ~127;
            meta[4 + e] = cp;   // padded count
            meta[8 + e] = off;  // segment offset
            off += cp;
        }
    }
}

__global__ __launch_bounds__(256) void fill_kernel(
    const int* __restrict__ top2, int* __restrict__ meta,
    int* __restrict__ toklist, int2* __restrict__ slotmap) {
    __shared__ int lc[4], base[4];
    if (threadIdx.x < 4) lc[threadIdx.x] = 0;
    __syncthreads();
    const int t = blockIdx.x * 256 + threadIdx.x;
    const int p = top2[t];
    const int e1 = p & 0xff, e2 = (p >> 8) & 0xff;
    const int r1 = atomicAdd(&lc[e1], 1);
    const int r2 = atomicAdd(&lc[e2], 1);
    __syncthreads();
    if (threadIdx.x < 4) base[threadIdx.x] = atomicAdd(&meta[12 + threadIdx.x], lc[threadIdx.x]);
    __syncthreads();
    const int p1 = meta[8 + e1] + base[e1] + r1;
    const int p2 = meta[8 + e2] + base[e2] + r2;
    toklist[p1] = t;
    toklist[p2] = t;
    slotmap[t] = make_int2(p1, p2);
}

// ---------------- fp32 -> f16 elementwise (x) ------------------------------
__global__ __launch_bounds__(256) void convert_f16_kernel(
    const float* __restrict__ in, f16* __restrict__ out, int n4) {
    const int i = blockIdx.x * 256 + threadIdx.x;
    if (i < n4) {
        const float4 v = ((const float4*)in)[i];
        f16x4 o = {(f16)v.x, (f16)v.y, (f16)v.z, (f16)v.w};
        ((f16x4*)out)[i] = o;
    }
}

// ---------------- fp32 [R][C] -> f16 [C][R] transpose (per z-expert) -------
__global__ __launch_bounds__(256) void transpose_f16_kernel(
    const float* __restrict__ in0, f16* __restrict__ out0, int R, int C) {
    __shared__ float tile[32][33];
    const float* in = in0 + (size_t)blockIdx.z * R * C;
    f16* out = out0 + (size_t)blockIdx.z * R * C;
    const int c0 = blockIdx.x * 32, r0 = blockIdx.y * 32;
    const int tx = threadIdx.x & 31;
    const int ty = threadIdx.x >> 5;  // 0..7
#pragma unroll
    for (int i = 0; i < 32; i += 8)
        tile[ty + i][tx] = in[(size_t)(r0 + ty + i) * C + c0 + tx];
    __syncthreads();
#pragma unroll
    for (int i = 0; i < 32; i += 8)
        out[(size_t)(c0 + ty + i) * R + r0 + tx] = (f16)tile[tx][ty + i];
}

// ------- 128x128 GEMM, reg-staged double-buffer, 1 barrier per k0 ---------
// Grid: x = m-tile (id%8 == m-residue => per-XCD L2-resident A set),
//       y = n-tile, z = expert.
// Pipeline: global->VGPR loads for k0+1 issue BEFORE the MFMA block on k0;
// the vmcnt wait is a data-dep of the ds_write, so it lands after compute —
// global latency is hidden in-wave (no reliance on multi-block overlap, and
// no vmcnt(0) drain at the barrier like the global_load_lds structure had).
// MODE 0: outH[off+m] = relu(A_gather x BT + b1)  (f16)
// MODE 1: yseg[off+m] = (h x BT + b2)  (f16 segments; combined later)
//         dense fallback (outH==null): atomicAdd(outF[m], wts[m][e]*v)
template <int MODE>
__global__ __launch_bounds__(256, 2) void gemm_kernel(
    const f16* __restrict__ A, const f16* __restrict__ BT,
    int N, int K,
    const float* __restrict__ bias,
    f16* __restrict__ outH, float* __restrict__ outF,
    const float* __restrict__ wts,
    const int* __restrict__ toklist, const int* __restrict__ meta, int e0) {
    __shared__ __align__(16) f16 As[2][128 * 64];
    __shared__ __align__(16) f16 Bs[2][128 * 64];
    const int zz = blockIdx.z;
    const int e = e0 + zz;
    const int m0 = blockIdx.x * 128, n0 = blockIdx.y * 128;

    int cnt = M_TOK, off = 0;
    if (meta) {
        cnt = meta[e];
        const int cp = meta[4 + e];
        off = meta[8 + e];
        if (m0 >= cp) return;
    }

    const f16* BTe = BT + (size_t)zz * N * K;
    const float* be = bias + (size_t)zz * N;

    const int tid = threadIdx.x;
    const int wave = tid >> 6, lane = tid & 63;
    const int wm = wave >> 1, wn = wave & 1;
    const int quad = lane >> 4, l16 = lane & 15;

    f32x4 acc[4][4] = {};

    // staging: round r -> local row lr = r*32 + (tid>>3); thread's LDS 16B
    // chunk position is tid&7, but it FETCHES global chunk (tid&7)^(lr&7):
    // row lr's LDS position p holds global chunk p^(lr&7) (bank spread).
    const int lrb = tid >> 3;                         // 0..31
    const int gcoff = (((tid & 7) ^ (lrb & 7)) * 8);  // swizzled k-elem offset
    const f16* ga[4];
    const f16* gb[4];
#pragma unroll
    for (int r = 0; r < 4; ++r) {
        const int lr = r * 32 + lrb;
        const int gm = m0 + lr;
        int arow;
        if (MODE == 0) arow = toklist ? toklist[off + gm] : gm;
        else arow = off + gm;
        ga[r] = A + (size_t)arow * K + gcoff;
        gb[r] = BTe + (size_t)(n0 + lr) * K + gcoff;
    }

    // prologue: stage k0=0 through regs into LDS[0]
    u32x4 ra[4], rb[4];
#pragma unroll
    for (int r = 0; r < 4; ++r) ra[r] = *(const u32x4*)(ga[r]);
#pragma unroll
    for (int r = 0; r < 4; ++r) rb[r] = *(const u32x4*)(gb[r]);
#pragma unroll
    for (int r = 0; r < 4; ++r) *(u32x4*)&As[0][(r * 256 + tid) * 8] = ra[r];
#pragma unroll
    for (int r = 0; r < 4; ++r) *(u32x4*)&Bs[0][(r * 256 + tid) * 8] = rb[r];
    __syncthreads();

    const int swl = l16 & 7;
    for (int k0 = 0; k0 < K; k0 += 64) {
        const int p = (k0 >> 6) & 1;
        // issue next tile's global loads NOW (overlap with MFMA below)
        const int kn = (k0 + 64 < K) ? (k0 + 64) : 0;  // last iter: dummy reload
#pragma unroll
        for (int r = 0; r < 4; ++r) ra[r] = *(const u32x4*)(ga[r] + kn);
#pragma unroll
        for (int r = 0; r < 4; ++r) rb[r] = *(const u32x4*)(gb[r] + kn);

#pragma unroll
        for (int kk = 0; kk < 64; kk += 32) {
            const int kc = kk >> 3;  // chunk base: 0 or 4
            f16x8 af[4], bf[4];
#pragma unroll
            for (int i = 0; i < 4; ++i)
                af[i] = *(const f16x8*)&As[p][(size_t)(wm * 64 + i * 16 + l16) * 64 +
                                             (((kc + quad) ^ swl) << 3)];
#pragma unroll
            for (int j = 0; j < 4; ++j)
                bf[j] = *(const f16x8*)&Bs[p][(size_t)(wn * 64 + j * 16 + l16) * 64 +
                                             (((kc + quad) ^ swl) << 3)];
#pragma unroll
            for (int i = 0; i < 4; ++i)
#pragma unroll
                for (int j = 0; j < 4; ++j)
                    acc[i][j] = __builtin_amdgcn_mfma_f32_16x16x32_f16(af[i], bf[j], acc[i][j], 0, 0, 0);
        }

        // stage next tile into the other buffer (vmcnt wait lands here)
#pragma unroll
        for (int r = 0; r < 4; ++r) *(u32x4*)&As[p ^ 1][(r * 256 + tid) * 8] = ra[r];
#pragma unroll
        for (int r = 0; r < 4; ++r) *(u32x4*)&Bs[p ^ 1][(r * 256 + tid) * 8] = rb[r];
        __syncthreads();  // all reads of LDS[p] and writes of LDS[p^1] done
    }

    // epilogue: C/D layout col = lane&15, row = quad*4 + reg
#pragma unroll
    for (int i = 0; i < 4; ++i) {
        const int mbase = m0 + wm * 64 + i * 16 + quad * 4;
#pragma unroll
        for (int j = 0; j < 4; ++j) {
            const int n = n0 + wn * 64 + j * 16 + l16;
            const float bv = be[n];
#pragma unroll
            for (int r = 0; r < 4; ++r) {
                const int m = mbase + r;
                float v = acc[i][j][r] + bv;
                if (MODE == 0) {
                    v = v > 0.0f ? v : 0.0f;
                    outH[(size_t)(off + m) * N + n] = (f16)v;
                } else {
                    if (outH) {  // sparse: f16 segment write (padded rows ok)
                        outH[(size_t)(off + m) * N + n] = (f16)v;
                    } else if (m < cnt) {  // dense fallback: weighted atomic
                        const float w = wts[m * 4 + e];
                        atomicAdd(&outF[(size_t)m * N + n], w * v);
                    }
                }
            }
        }
    }
}

// ---------------- combine: out[t] = w1*yseg[p1] + w2*yseg[p2] --------------
__global__ __launch_bounds__(256) void combine_kernel(
    const f16* __restrict__ yseg, const int2* __restrict__ slotmap,
    const float2* __restrict__ wpair, float* __restrict__ out, int aux_idx) {
    const int t = blockIdx.x;
    const int2 p = slotmap[t];
    const float2 w = wpair[t];
    const int d = threadIdx.x * 4;
    const f16x4 a = *(const f16x4*)&yseg[(size_t)p.x * DDIM + d];
    const f16x4 b = *(const f16x4*)&yseg[(size_t)p.y * DDIM + d];
    float4 o;
    o.x = w.x * (float)a[0] + w.y * (float)b[0];
    o.y = w.x * (float)a[1] + w.y * (float)b[1];
    o.z = w.x * (float)a[2] + w.y * (float)b[2];
    o.w = w.x * (float)a[3] + w.y * (float)b[3];
    *(float4*)&out[(size_t)t * DDIM + d] = o;
    if (t == 0 && threadIdx.x == 0 && aux_idx >= 0) out[aux_idx] = 0.0f;
}

extern "C" void kernel_launch(void* const* d_in, const int* in_sizes, int n_in,
                              void* d_out, int out_size, void* d_ws, size_t ws_size,
                              hipStream_t stream) {
    (void)in_sizes; (void)n_in;
    const float* x  = (const float*)d_in[0];
    const float* Wr = (const float*)d_in[1];
    const float* W1 = (const float*)d_in[2];
    const float* b1 = (const float*)d_in[3];
    const float* W2 = (const float*)d_in[4];
    const float* b2 = (const float*)d_in[5];
    float* out = (float*)d_out;

    char* ws = (char*)d_ws;
    float*  wts   = (float*)ws;                     // [0,128K)
    int*    meta  = (int*)(ws + (128 << 10));       // [128K,132K)
    int*    top2  = (int*)(ws + (132 << 10));       // [132K,164K)
    int*    tokl  = (int*)(ws + (164 << 10));       // [164K,232K) TOTPAD ints
    float2* wpair = (float2*)(ws + (240 << 10));    // [240K,304K)
    int2*   slotm = (int2*)(ws + (304 << 10));      // [304K,368K)
    f16*    xb    = (f16*)(ws + (512 << 10));       // 16 MB
    const size_t MBs = 1ull << 20;
    const size_t base = (512 << 10) + 16 * MBs;

    const size_t SPARSE_NEED = (512 << 10) + 80 * MBs + (size_t)TOTPAD * HDIM * sizeof(f16);
    const bool sparse = ws_size >= SPARSE_NEED;

    const int aux_idx = (out_size == M_TOK * DDIM + 1) ? (M_TOK * DDIM) : -1;

    f16 *w1t, *w2t, *h, *yseg;
    if (sparse) {
        w1t  = (f16*)(ws + base);             // 32 MB [E][H][D]
        w2t  = (f16*)(ws + base + 32 * MBs);  // 32 MB [E][D][H]
        h    = (f16*)(ws + base + 64 * MBs);  // 138.4 MB (TOTPAD x HDIM)
        yseg = (f16*)(ws + (512 << 10));      // 34.6 MB overlay on xb+w1t
                                              // (both dead before gemm<1> runs)
    } else {
        w1t = (f16*)(ws + base);             // 8 MB, per-expert reuse
        w2t = (f16*)(ws + base + 8 * MBs);   // 8 MB
        h   = (f16*)(ws + base + 16 * MBs);  // 64 MB
        yseg = nullptr;
    }

    router_kernel<<<M_TOK / 4, 256, 0, stream>>>(x, Wr, wts, top2, wpair);
    convert_f16_kernel<<<(M_TOK * DDIM / 4) / 256, 256, 0, stream>>>(x, xb, M_TOK * DDIM / 4);

    if (sparse) {
        hipMemsetAsync(meta, 0, 16 * sizeof(int), stream);
        hipMemsetAsync(tokl, 0, (size_t)TOTPAD * sizeof(int), stream);
        count_kernel<<<M_TOK / 256, 256, 0, stream>>>(top2, meta);
        offsets_kernel<<<1, 64, 0, stream>>>(meta);
        fill_kernel<<<M_TOK / 256, 256, 0, stream>>>(top2, meta, tokl, slotm);
        transpose_f16_kernel<<<dim3(HDIM / 32, DDIM / 32, NEXP), 256, 0, stream>>>(W1, w1t, DDIM, HDIM);
        transpose_f16_kernel<<<dim3(DDIM / 32, HDIM / 32, NEXP), 256, 0, stream>>>(W2, w2t, HDIM, DDIM);
        // h = relu(x_gather @ W1 + b1), per-expert packed segments
        gemm_kernel<0><<<dim3(M_TOK / 128, HDIM / 128, NEXP), 256, 0, stream>>>(
            xb, w1t, HDIM, DDIM, b1, h, nullptr, wts, tokl, meta, 0);
        // yseg = h @ W2 + b2 (f16 segments; yseg overlays xb/w1t — both dead)
        gemm_kernel<1><<<dim3(M_TOK / 128, DDIM / 128, NEXP), 256, 0, stream>>>(
            h, w2t, DDIM, HDIM, b2, yseg, nullptr, wts, tokl, meta, 0);
        combine_kernel<<<M_TOK, 256, 0, stream>>>(yseg, slotm, wpair, out, aux_idx);
    } else {
        hipMemsetAsync(out, 0, (size_t)out_size * sizeof(float), stream);
        for (int e = 0; e < NEXP; ++e) {
            transpose_f16_kernel<<<dim3(HDIM / 32, DDIM / 32, 1), 256, 0, stream>>>(
                W1 + (size_t)e * DDIM * HDIM, w1t, DDIM, HDIM);
            gemm_kernel<0><<<dim3(M_TOK / 128, HDIM / 128, 1), 256, 0, stream>>>(
                xb, w1t, HDIM, DDIM, b1 + (size_t)e * HDIM, h, nullptr, wts, nullptr, nullptr, e);
            transpose_f16_kernel<<<dim3(DDIM / 32, HDIM / 32, 1), 256, 0, stream>>>(
                W2 + (size_t)e * HDIM * DDIM, w2t, HDIM, DDIM);
            gemm_kernel<1><<<dim3(M_TOK / 128, DDIM / 128, 1), 256, 0, stream>>>(
                h, w2t, DDIM, HDIM, b2 + (size_t)e * DDIM, nullptr, out, wts, nullptr, nullptr, e);
        }
    }
}

// Round 6
// 675.554 us; speedup vs baseline: 1.1175x; 1.1175x over previous
//
#include <hip/hip_runtime.h>
#include <cstdint>
#include <cstddef>

typedef _Float16 f16;
typedef __attribute__((ext_vector_type(8))) f16 f16x8;
typedef __attribute__((ext_vector_type(4))) f16 f16x4;
typedef __attribute__((ext_vector_type(4))) float f32x4;

#define M_TOK 8192
#define DDIM 1024
#define HDIM 4096
#define NEXP 4
#define TOTPAD 16896  // >= 16384 + 4*127, rounded to 128

// async global->LDS, 16B per lane (global address may be per-lane; LDS dest
// must be wave-uniform base + lane*16 — our mapping is exactly that).
__device__ __forceinline__ void async_copy16(const void* g, void* s) {
    __builtin_amdgcn_global_load_lds((__attribute__((address_space(1))) void*)g,
                                     (__attribute__((address_space(3))) void*)s,
                                     16, 0, 0);
}

// ---------------- Router: logits -> top2 softmax weights ------------------
__global__ __launch_bounds__(256) void router_kernel(
    const float* __restrict__ x, const float* __restrict__ Wr,
    float* __restrict__ wts, int* __restrict__ top2, float2* __restrict__ wpair) {
    __shared__ float wr_s[DDIM * NEXP];
    for (int i = threadIdx.x; i < DDIM * NEXP; i += 256) wr_s[i] = Wr[i];
    __syncthreads();
    const int wave = threadIdx.x >> 6, lane = threadIdx.x & 63;
    const int t = blockIdx.x * 4 + wave;
    float a0 = 0.f, a1 = 0.f, a2 = 0.f, a3 = 0.f;
    const float* xr = x + (size_t)t * DDIM;
    for (int i = 0; i < DDIM; i += 256) {
        const int d = i + lane * 4;
        const float4 v = *(const float4*)(xr + d);
        const float* w0 = &wr_s[d * 4];
        a0 += v.x * w0[0] + v.y * w0[4] + v.z * w0[8]  + v.w * w0[12];
        a1 += v.x * w0[1] + v.y * w0[5] + v.z * w0[9]  + v.w * w0[13];
        a2 += v.x * w0[2] + v.y * w0[6] + v.z * w0[10] + v.w * w0[14];
        a3 += v.x * w0[3] + v.y * w0[7] + v.z * w0[11] + v.w * w0[15];
    }
    for (int off = 32; off > 0; off >>= 1) {
        a0 += __shfl_xor(a0, off, 64);
        a1 += __shfl_xor(a1, off, 64);
        a2 += __shfl_xor(a2, off, 64);
        a3 += __shfl_xor(a3, off, 64);
    }
    if (lane == 0) {
        float lg[4] = {a0, a1, a2, a3};
        int i1 = 0;
        for (int e = 1; e < 4; ++e) if (lg[e] > lg[i1]) i1 = e;
        int i2 = -1;
        for (int e = 0; e < 4; ++e) {
            if (e == i1) continue;
            if (i2 < 0 || lg[e] > lg[i2]) i2 = e;
        }
        const float w1 = 1.0f / (1.0f + expf(lg[i2] - lg[i1]));
        float w[4] = {0.f, 0.f, 0.f, 0.f};
        w[i1] = w1; w[i2] = 1.0f - w1;
        float* o = wts + (size_t)t * 4;
        o[0] = w[0]; o[1] = w[1]; o[2] = w[2]; o[3] = w[3];
        top2[t] = i1 | (i2 << 8);
        wpair[t] = make_float2(w1, 1.0f - w1);
    }
}

// ---------------- count / offsets / fill (sparse routing lists) -----------
__global__ __launch_bounds__(256) void count_kernel(
    const int* __restrict__ top2, int* __restrict__ meta) {
    __shared__ int lc[4];
    if (threadIdx.x < 4) lc[threadIdx.x] = 0;
    __syncthreads();
    const int t = blockIdx.x * 256 + threadIdx.x;
    const int p = top2[t];
    atomicAdd(&lc[p & 0xff], 1);
    atomicAdd(&lc[(p >> 8) & 0xff], 1);
    __syncthreads();
    if (threadIdx.x < 4) atomicAdd(&meta[threadIdx.x], lc[threadIdx.x]);
}

__global__ void offsets_kernel(int* __restrict__ meta) {
    if (threadIdx.x == 0) {
        int off = 0;
        for (int e = 0; e < 4; ++e) {
            const int c = meta[e];
            const int cp = (c + 127) & ~127;
            meta[4 + e] = cp;   // padded count
            meta[8 + e] = off;  // segment offset
            off += cp;
        }
    }
}

__global__ __launch_bounds__(256) void fill_kernel(
    const int* __restrict__ top2, int* __restrict__ meta,
    int* __restrict__ toklist, int2* __restrict__ slotmap) {
    __shared__ int lc[4], base[4];
    if (threadIdx.x < 4) lc[threadIdx.x] = 0;
    __syncthreads();
    const int t = blockIdx.x * 256 + threadIdx.x;
    const int p = top2[t];
    const int e1 = p & 0xff, e2 = (p >> 8) & 0xff;
    const int r1 = atomicAdd(&lc[e1], 1);
    const int r2 = atomicAdd(&lc[e2], 1);
    __syncthreads();
    if (threadIdx.x < 4) base[threadIdx.x] = atomicAdd(&meta[12 + threadIdx.x], lc[threadIdx.x]);
    __syncthreads();
    const int p1 = meta[8 + e1] + base[e1] + r1;
    const int p2 = meta[8 + e2] + base[e2] + r2;
    toklist[p1] = t;
    toklist[p2] = t;
    slotmap[t] = make_int2(p1, p2);
}

// ---------------- fp32 -> f16 elementwise (x) ------------------------------
__global__ __launch_bounds__(256) void convert_f16_kernel(
    const float* __restrict__ in, f16* __restrict__ out, int n4) {
    const int i = blockIdx.x * 256 + threadIdx.x;
    if (i < n4) {
        const float4 v = ((const float4*)in)[i];
        f16x4 o = {(f16)v.x, (f16)v.y, (f16)v.z, (f16)v.w};
        ((f16x4*)out)[i] = o;
    }
}

// -------- pack W [K][N] fp32 -> fragment-major f16 B (per z-expert) --------
// B[n][k] = W[k][n].  Output f16 index:
//   I(n,k) = (n16*(K/64) + k0b)*1024 + kk2*512 + quad*128 + l16*8 + j
// where n16=n/16, l16=n%16, k0b=k/64, kk2=(k%64)/32, quad=(k%32)/8, j=k%8.
// A wave's B-fragment load is then frag_base + lane*16B (perfectly coalesced).
// Tile = 64k x 64n = 512 sixteen-byte chunks => exactly 2 rounds of 256 thr.
__global__ __launch_bounds__(256) void pack_b_kernel(
    const float* __restrict__ in0, f16* __restrict__ out0, int K, int N) {
    __shared__ float tile[64][65];
    const float* in = in0 + (size_t)blockIdx.z * K * N;
    f16* out = out0 + (size_t)blockIdx.z * K * N;
    const int n0 = blockIdx.x * 64, k0 = blockIdx.y * 64;
    const int tx = threadIdx.x & 63, ty = threadIdx.x >> 6;  // ty 0..3
#pragma unroll
    for (int i = 0; i < 64; i += 4)
        tile[ty + i][tx] = in[(size_t)(k0 + ty + i) * N + n0 + tx];
    __syncthreads();
#pragma unroll
    for (int c = 0; c < 2; ++c) {                   // 512 chunks total (BUGFIX: was 4)
        const int cc = c * 256 + threadIdx.x;       // 0..511: 16B chunk id
        const int grp = cc >> 7;                    // n-16-group within tile (0..3)
        const int within = cc & 127;                // kk2*64 + quad*16 + l16
        const int kk2 = within >> 6, quad = (within >> 4) & 3, l16 = within & 15;
        const int nl = grp * 16 + l16;
        const int kl = kk2 * 32 + quad * 8;
        f16x8 v;
#pragma unroll
        for (int j = 0; j < 8; ++j) v[j] = (f16)tile[kl + j][nl];
        const size_t o = ((size_t)(n0 / 16 + grp) * (K >> 6) + (k0 >> 6)) * 1024 +
                         (size_t)within * 8;
        *(f16x8*)&out[o] = v;
    }
}

// ------ 128x128 GEMM: A via LDS (dbuf, 1 barrier/iter), B via registers ----
// Grid: x = m-tile (id%8 == m-residue => per-XCD L2 A locality), y = n-tile,
// z = expert.  B comes from the fragment-major pack (no LDS, no barrier dep).
// MODE 0: outH[off+m] = relu(A_gather x B + b1)  (f16)
// MODE 1: outH[off+m] = (h x B + b2) (f16 segments; combined later)
//         dense fallback (outH==null): atomicAdd(outF[m], wts[m][e]*v)
template <int MODE>
__global__ __launch_bounds__(256, 3) void gemm_kernel(
    const f16* __restrict__ A, const f16* __restrict__ Bswz,
    int N, int K,
    const float* __restrict__ bias,
    f16* __restrict__ outH, float* __restrict__ outF,
    const float* __restrict__ wts,
    const int* __restrict__ toklist, const int* __restrict__ meta, int e0) {
    __shared__ __align__(16) f16 As[2][128 * 64];
    const int zz = blockIdx.z;
    const int e = e0 + zz;
    const int m0 = blockIdx.x * 128, n0 = blockIdx.y * 128;

    int cnt = M_TOK, off = 0;
    if (meta) {
        cnt = meta[e];
        const int cp = meta[4 + e];
        off = meta[8 + e];
        if (m0 >= cp) return;
    }

    const f16* Be = Bswz + (size_t)zz * N * K;
    const float* be = bias + (size_t)zz * N;

    const int tid = threadIdx.x;
    const int wave = tid >> 6, lane = tid & 63;
    const int wm = wave >> 1, wn = wave & 1;
    const int quad = lane >> 4, l16 = lane & 15;
    const int Kb = K >> 6;  // k0-blocks

    f32x4 acc[4][4] = {};

    // A staging (XOR-swizzled, proven r3): round r -> row lr = r*32+(tid>>3);
    // LDS chunk pos tid&7 holds global chunk (tid&7)^(lr&7).
    const int lrb = tid >> 3;
    const int gcoff = (((tid & 7) ^ (lrb & 7)) * 8);
    const f16* ga[4];
#pragma unroll
    for (int r = 0; r < 4; ++r) {
        const int gm = m0 + r * 32 + lrb;
        int arow;
        if (MODE == 0) arow = toklist ? toklist[off + gm] : gm;
        else arow = off + gm;
        ga[r] = A + (size_t)arow * K + gcoff;
    }

    // B fragment pointers: frag(j, k0, kk2) = bp[j] + (k0>>6)*1024 + kk2*512
    const f16* bp[4];
#pragma unroll
    for (int j = 0; j < 4; ++j)
        bp[j] = Be + ((size_t)(n0 / 16 + wn * 4 + j) * Kb) * 1024 + lane * 8;

    // prologue: stage A(k0=0) into As[0]
#pragma unroll
    for (int r = 0; r < 4; ++r)
        async_copy16(ga[r], &As[0][(r * 256 + tid) * 8]);
    __syncthreads();

    const int swl = l16 & 7;
    int p = 0;
    for (int k0b = 0; k0b < Kb; ++k0b) {
        // B fragments for this k0 first (global->VGPR, L2-served) so their
        // use-wait is vmcnt(<A-prefetch count>), not a full drain
        f16x8 bf[2][4];
#pragma unroll
        for (int kk2 = 0; kk2 < 2; ++kk2)
#pragma unroll
            for (int j = 0; j < 4; ++j)
                bf[kk2][j] = *(const f16x8*)(bp[j] + (k0b << 10) + (kk2 << 9));

        // prefetch A(next) into the other buffer — full MFMA phase to land
        if (k0b + 1 < Kb) {
            const int kn = (k0b + 1) << 6;
#pragma unroll
            for (int r = 0; r < 4; ++r)
                async_copy16(ga[r] + kn, &As[p ^ 1][(r * 256 + tid) * 8]);
        }

#pragma unroll
        for (int kk2 = 0; kk2 < 2; ++kk2) {
            f16x8 af[4];
#pragma unroll
            for (int i = 0; i < 4; ++i)
                af[i] = *(const f16x8*)&As[p][(size_t)(wm * 64 + i * 16 + l16) * 64 +
                                             (((kk2 * 4 + quad) ^ swl) << 3)];
#pragma unroll
            for (int i = 0; i < 4; ++i)
#pragma unroll
                for (int j = 0; j < 4; ++j)
                    acc[i][j] = __builtin_amdgcn_mfma_f32_16x16x32_f16(af[i], bf[kk2][j], acc[i][j], 0, 0, 0);
        }
        __syncthreads();  // reads of As[p] done; prefetched As[p^1] drained
        p ^= 1;
    }

    // epilogue: C/D layout col = lane&15, row = quad*4 + reg
#pragma unroll
    for (int i = 0; i < 4; ++i) {
        const int mbase = m0 + wm * 64 + i * 16 + quad * 4;
#pragma unroll
        for (int j = 0; j < 4; ++j) {
            const int n = n0 + wn * 64 + j * 16 + l16;
            const float bv = be[n];
#pragma unroll
            for (int r = 0; r < 4; ++r) {
                const int m = mbase + r;
                float v = acc[i][j][r] + bv;
                if (MODE == 0) {
                    v = v > 0.0f ? v : 0.0f;
                    outH[(size_t)(off + m) * N + n] = (f16)v;
                } else {
                    if (outH) {  // sparse: f16 segment write (padded rows ok)
                        outH[(size_t)(off + m) * N + n] = (f16)v;
                    } else if (m < cnt) {  // dense fallback: weighted atomic
                        const float w = wts[m * 4 + e];
                        atomicAdd(&outF[(size_t)m * N + n], w * v);
                    }
                }
            }
        }
    }
}

// ---------------- combine: out[t] = w1*yseg[p1] + w2*yseg[p2] --------------
__global__ __launch_bounds__(256) void combine_kernel(
    const f16* __restrict__ yseg, const int2* __restrict__ slotmap,
    const float2* __restrict__ wpair, float* __restrict__ out, int aux_idx) {
    const int t = blockIdx.x;
    const int2 p = slotmap[t];
    const float2 w = wpair[t];
    const int d = threadIdx.x * 4;
    const f16x4 a = *(const f16x4*)&yseg[(size_t)p.x * DDIM + d];
    const f16x4 b = *(const f16x4*)&yseg[(size_t)p.y * DDIM + d];
    float4 o;
    o.x = w.x * (float)a[0] + w.y * (float)b[0];
    o.y = w.x * (float)a[1] + w.y * (float)b[1];
    o.z = w.x * (float)a[2] + w.y * (float)b[2];
    o.w = w.x * (float)a[3] + w.y * (float)b[3];
    *(float4*)&out[(size_t)t * DDIM + d] = o;
    if (t == 0 && threadIdx.x == 0 && aux_idx >= 0) out[aux_idx] = 0.0f;
}

extern "C" void kernel_launch(void* const* d_in, const int* in_sizes, int n_in,
                              void* d_out, int out_size, void* d_ws, size_t ws_size,
                              hipStream_t stream) {
    (void)in_sizes; (void)n_in;
    const float* x  = (const float*)d_in[0];
    const float* Wr = (const float*)d_in[1];
    const float* W1 = (const float*)d_in[2];
    const float* b1 = (const float*)d_in[3];
    const float* W2 = (const float*)d_in[4];
    const float* b2 = (const float*)d_in[5];
    float* out = (float*)d_out;

    char* ws = (char*)d_ws;
    float*  wts   = (float*)ws;                     // [0,128K)
    int*    meta  = (int*)(ws + (128 << 10));       // [128K,132K)
    int*    top2  = (int*)(ws + (132 << 10));       // [132K,164K)
    int*    tokl  = (int*)(ws + (164 << 10));       // [164K,232K) TOTPAD ints
    float2* wpair = (float2*)(ws + (240 << 10));    // [240K,304K)
    int2*   slotm = (int2*)(ws + (304 << 10));      // [304K,368K)
    f16*    xb    = (f16*)(ws + (512 << 10));       // 16 MB
    const size_t MBs = 1ull << 20;
    const size_t base = (512 << 10) + 16 * MBs;

    const size_t SPARSE_NEED = (512 << 10) + 80 * MBs + (size_t)TOTPAD * HDIM * sizeof(f16);
    const bool sparse = ws_size >= SPARSE_NEED;

    const int aux_idx = (out_size == M_TOK * DDIM + 1) ? (M_TOK * DDIM) : -1;

    f16 *w1t, *w2t, *h, *yseg;
    if (sparse) {
        w1t  = (f16*)(ws + base);             // 32 MB [E] fragment-major B1
        w2t  = (f16*)(ws + base + 32 * MBs);  // 32 MB [E] fragment-major B2
        h    = (f16*)(ws + base + 64 * MBs);  // 138.4 MB (TOTPAD x HDIM)
        yseg = (f16*)(ws + (512 << 10));      // 34.6 MB overlay on xb+w1t
                                              // (both dead before gemm<1> runs)
    } else {
        w1t = (f16*)(ws + base);             // 8 MB, per-expert reuse
        w2t = (f16*)(ws + base + 8 * MBs);   // 8 MB
        h   = (f16*)(ws + base + 16 * MBs);  // 64 MB
        yseg = nullptr;
    }

    router_kernel<<<M_TOK / 4, 256, 0, stream>>>(x, Wr, wts, top2, wpair);
    convert_f16_kernel<<<(M_TOK * DDIM / 4) / 256, 256, 0, stream>>>(x, xb, M_TOK * DDIM / 4);

    if (sparse) {
        hipMemsetAsync(meta, 0, 16 * sizeof(int), stream);
        hipMemsetAsync(tokl, 0, (size_t)TOTPAD * sizeof(int), stream);
        count_kernel<<<M_TOK / 256, 256, 0, stream>>>(top2, meta);
        offsets_kernel<<<1, 64, 0, stream>>>(meta);
        fill_kernel<<<M_TOK / 256, 256, 0, stream>>>(top2, meta, tokl, slotm);
        // fragment-major weight packs (replaces transposes)
        pack_b_kernel<<<dim3(HDIM / 64, DDIM / 64, NEXP), 256, 0, stream>>>(W1, w1t, DDIM, HDIM);
        pack_b_kernel<<<dim3(DDIM / 64, HDIM / 64, NEXP), 256, 0, stream>>>(W2, w2t, HDIM, DDIM);
        // h = relu(x_gather @ W1 + b1), per-expert packed segments
        gemm_kernel<0><<<dim3(M_TOK / 128, HDIM / 128, NEXP), 256, 0, stream>>>(
            xb, w1t, HDIM, DDIM, b1, h, nullptr, wts, tokl, meta, 0);
        // yseg = h @ W2 + b2 (f16 segments; yseg overlays xb/w1t — both dead)
        gemm_kernel<1><<<dim3(M_TOK / 128, DDIM / 128, NEXP), 256, 0, stream>>>(
            h, w2t, DDIM, HDIM, b2, yseg, nullptr, wts, tokl, meta, 0);
        combine_kernel<<<M_TOK, 256, 0, stream>>>(yseg, slotm, wpair, out, aux_idx);
    } else {
        hipMemsetAsync(out, 0, (size_t)out_size * sizeof(float), stream);
        for (int e = 0; e < NEXP; ++e) {
            pack_b_kernel<<<dim3(HDIM / 64, DDIM / 64, 1), 256, 0, stream>>>(
                W1 + (size_t)e * DDIM * HDIM, w1t, DDIM, HDIM);
            gemm_kernel<0><<<dim3(M_TOK / 128, HDIM / 128, 1), 256, 0, stream>>>(
                xb, w1t, HDIM, DDIM, b1 + (size_t)e * HDIM, h, nullptr, wts, nullptr, nullptr, e);
            pack_b_kernel<<<dim3(DDIM / 64, HDIM / 64, 1), 256, 0, stream>>>(
                W2 + (size_t)e * HDIM * DDIM, w2t, HDIM, DDIM);
            gemm_kernel<1><<<dim3(M_TOK / 128, DDIM / 128, 1), 256, 0, stream>>>(
                h, w2t, DDIM, HDIM, b2 + (size_t)e * DDIM, nullptr, out, wts, nullptr, nullptr, e);
        }
    }
}